// Round 7
// baseline (2751.841 us; speedup 1.0000x reference)
//
#include <hip/hip_runtime.h>
#include <hip/hip_bf16.h>
#include <cstdint>
#include <cstddef>

typedef __bf16 bf16_t;
typedef __bf16 bf16x8 __attribute__((ext_vector_type(8)));
typedef float f32x4 __attribute__((ext_vector_type(4)));
typedef unsigned int u32;
typedef u32 u32x4 __attribute__((ext_vector_type(4)));

#define H_DIM 4096
#define I_DIM 11008

__device__ __forceinline__ u32 pack_bf16(float a, float b) {
    union { __bf16 h[2]; u32 u; } r;
    r.h[0] = (__bf16)a;
    r.h[1] = (__bf16)b;
    return r.u;
}

// async global->LDS: each lane 16B; LDS dest = wave-uniform base + lane*16
__device__ __forceinline__ void gload16(const bf16_t* g, char* l) {
    __builtin_amdgcn_global_load_lds(
        (const __attribute__((address_space(1))) u32*)g,
        (__attribute__((address_space(3))) u32*)l, 16, 0, 0);
}

#define ASM_VMCNT6 asm volatile("s_waitcnt vmcnt(6)" ::: "memory")
#define ASM_VMCNT3 asm volatile("s_waitcnt vmcnt(3)" ::: "memory")
#define ASM_VMCNT0 asm volatile("s_waitcnt vmcnt(0)" ::: "memory")
#define ASM_LGKM0  asm volatile("s_waitcnt lgkmcnt(0)" ::: "memory")
#define ASM_BAR    asm volatile("s_barrier" ::: "memory")

// bijective chunked XCD swizzle (total % 8 == 0), then n-fastest decode.
__device__ __forceinline__ void decode_tile(int NBN, int& mt, int& nt) {
    int b = (int)blockIdx.x;
    const int total = (int)gridDim.x;
    if ((total & 7) == 0) {
        const int q = total >> 3;
        b = (b & 7) * q + (b >> 3);   // contiguous chunk per XCD
    }
    mt = b / NBN;
    nt = b - mt * NBN;
}

// ============================================================================
// dequant + pack: Q[K][N] int codes, S[K/128][N] -> W packed fragment order.
// Block handles one B-block (32 k x 128 n). Packed unit (cg,lane) holds
// element (n = cg*16 + (lane&15), k = (lane>>4)*8 + e), block stride 4096 elems.
// ============================================================================
__global__ __launch_bounds__(256) void k_dequant_pack(const int* __restrict__ Q,
                                                      const float* __restrict__ S,
                                                      bf16_t* __restrict__ W,
                                                      int K, int N) {
    __shared__ bf16_t tile[128][40];  // [n][k], 80B rows (16B aligned, bank-spread)
    const int tid = threadIdx.x;
    const int k0 = blockIdx.x * 32, n0 = blockIdx.y * 128;
    const int grp = k0 >> 7;
    const int c4 = (tid & 31) * 4;
    const int kr = tid >> 5;
    float4 sc = *(const float4*)(S + (size_t)grp * N + n0 + c4);
#pragma unroll
    for (int p = 0; p < 4; ++p) {
        const int k = kr + p * 8;
        int4 q = *(const int4*)(Q + (size_t)(k0 + k) * N + n0 + c4);
        tile[c4 + 0][k] = (bf16_t)fmaf((float)q.x, sc.x, -8.f * sc.x);
        tile[c4 + 1][k] = (bf16_t)fmaf((float)q.y, sc.y, -8.f * sc.y);
        tile[c4 + 2][k] = (bf16_t)fmaf((float)q.z, sc.z, -8.f * sc.z);
        tile[c4 + 3][k] = (bf16_t)fmaf((float)q.w, sc.w, -8.f * sc.w);
    }
    __syncthreads();
    bf16_t* blk = W + (((size_t)blockIdx.y * (K / 32) + blockIdx.x) << 12);
#pragma unroll
    for (int j = 0; j < 2; ++j) {
        const int u = j * 256 + tid;
        const int cg = u >> 6, ln = u & 63;
        u32x4 v = *(const u32x4*)((const char*)tile +
                                  (size_t)(cg * 16 + (ln & 15)) * 80 + (ln >> 4) * 16);
        *(u32x4*)(blk + (cg << 9) + (ln << 3)) = v;
    }
}

// ============================================================================
// fused gate+up GEMM. A = x (f32, reg-staged + cvt), B0/B1 packed bf16.
// BM=256 BN=128 BK=32, 8 waves (4x2), 4-buf LDS ring, 1 barrier/tile.
// Out: h = silu(x*Wg)*(x*Wu), bf16, packed as down-GEMM A fragments.
// ============================================================================
template <int KDIM>
__global__ __launch_bounds__(512, 2) void k_gateup(const float* __restrict__ x,
                                                   const bf16_t* __restrict__ Wg,
                                                   const bf16_t* __restrict__ Wu,
                                                   bf16_t* __restrict__ hp, int Nb) {
    constexpr int NT = KDIM / 32;
    __shared__ char smem[131072];  // A: 4x16KB @0; B0: 4x8KB @64K; B1: 4x8KB @96K

    const int tid = threadIdx.x, lane = tid & 63, wid = tid >> 6;
    const int wr = wid >> 1, wc = wid & 1;
    int mt, ntile;
    decode_tile(Nb >> 7, mt, ntile);
    const int m0 = mt * 256, n0 = ntile * 128;

    f32x4 accg[4][4], accu[4][4];
#pragma unroll
    for (int i = 0; i < 4; ++i)
#pragma unroll
        for (int j = 0; j < 4; ++j) { accg[i][j] = (f32x4)0.f; accu[i][j] = (f32x4)0.f; }

    // x staging: thread covers row (tid>>1), 16 f32 at (tid&1)*16 within k-tile
    const int arow = tid >> 1, ahalf = tid & 1;
    const float* xsrc = x + (size_t)(m0 + arow) * KDIM + ahalf * 16;
    const u32 wa0 = (u32)(((arow >> 4) << 10) | (((ahalf * 2) * 16 + (arow & 15)) << 4));
    const u32 wa1 = wa0 + 256;

    const bf16_t* wgB = Wg + (((size_t)ntile * NT) << 12);
    const bf16_t* wuB = Wu + (((size_t)ntile * NT) << 12);
    const u32 bsegG = (u32)((wid << 9) + (lane << 3));  // elems (global src)
    const u32 bsegL = (u32)(wid << 10);                 // bytes (LDS dest base)

    f32x4 preA[4], preB[4];

    auto issueB = [&](int kt) {
        char* b0 = smem + 65536 + ((kt & 3) << 13) + bsegL;
        char* b1 = smem + 98304 + ((kt & 3) << 13) + bsegL;
        gload16(wgB + (((size_t)kt) << 12) + bsegG, b0);
        gload16(wuB + (((size_t)kt) << 12) + bsegG, b1);
    };
    auto issueF = [&](int kt, f32x4 (&pre)[4]) {
        const float* s = xsrc + (size_t)kt * 32;
#pragma unroll
        for (int i = 0; i < 4; ++i) pre[i] = *(const f32x4*)(s + i * 4);
    };
    auto dswriteA = [&](int t1, f32x4 (&pre)[4]) {
        u32x4 w0, w1;
        w0.x = pack_bf16(pre[0].x, pre[0].y); w0.y = pack_bf16(pre[0].z, pre[0].w);
        w0.z = pack_bf16(pre[1].x, pre[1].y); w0.w = pack_bf16(pre[1].z, pre[1].w);
        w1.x = pack_bf16(pre[2].x, pre[2].y); w1.y = pack_bf16(pre[2].z, pre[2].w);
        w1.z = pack_bf16(pre[3].x, pre[3].y); w1.w = pack_bf16(pre[3].z, pre[3].w);
        char* ab = smem + ((t1 & 3) << 14);
        *(u32x4*)(ab + wa0) = w0;
        *(u32x4*)(ab + wa1) = w1;
    };

    auto tile_body = [&](int t, f32x4 (&pre)[4]) {
        const char* abuf = smem + ((t & 3) << 14);
        const char* b0buf = smem + 65536 + ((t & 3) << 13);
        const char* b1buf = smem + 98304 + ((t & 3) << 13);
        const u32 fo = (u32)(lane << 4);
        bf16x8 fa[4], f0[4], f1[4];
#pragma unroll
        for (int f = 0; f < 4; ++f) {
            fa[f] = *(const bf16x8*)(abuf + (((wr * 4 + f) << 10) + fo));
            f0[f] = *(const bf16x8*)(b0buf + (((wc * 4 + f) << 10) + fo));
            f1[f] = *(const bf16x8*)(b1buf + (((wc * 4 + f) << 10) + fo));
        }
        if (t <= NT - 3) { ASM_VMCNT6; } else { ASM_VMCNT0; }
        if (t + 1 < NT) dswriteA(t + 1, pre);
        if (t + 3 < NT) { issueB(t + 3); issueF(t + 3, pre); }
        // NO full lgkm drain here: compiler inserts fine-grained lgkmcnt per
        // MFMA operand, so MFMA starts as soon as the first fragments land.
        __builtin_amdgcn_s_setprio(1);
#pragma unroll
        for (int fn = 0; fn < 4; ++fn)
#pragma unroll
            for (int fm = 0; fm < 4; ++fm) {
                accg[fm][fn] = __builtin_amdgcn_mfma_f32_16x16x32_bf16(fa[fm], f0[fn], accg[fm][fn], 0, 0, 0);
                accu[fm][fn] = __builtin_amdgcn_mfma_f32_16x16x32_bf16(fa[fm], f1[fn], accu[fm][fn], 0, 0, 0);
            }
        __builtin_amdgcn_s_setprio(0);
        ASM_LGKM0;  // drain ds_writes (+ residual reads) before raw barrier
        ASM_BAR;
    };

    // prologue: batches 0,1 in flight; A(0) written; batch 2 issued
    issueB(0); issueF(0, preA);
    issueB(1); issueF(1, preB);
    ASM_VMCNT6;               // batch0 landed
    dswriteA(0, preA);
    issueB(2); issueF(2, preA);
    ASM_LGKM0;
    ASM_BAR;

    for (int t = 0; t < NT; t += 2) {
        tile_body(t, preB);       // consumes f(t+1) (odd set), refills with f(t+3)
        tile_body(t + 1, preA);   // consumes f(t+2) (even set), refills with f(t+4)
    }

    // ---- epilogue: silu(g)*u -> bf16, bounce via LDS, write packed h ----
    bf16_t* bounce = (bf16_t*)smem;  // [256][136] bf16 = 69632B
    const int ehr = lane >> 4, col16 = lane & 15;
#pragma unroll
    for (int fm = 0; fm < 4; ++fm)
#pragma unroll
        for (int fn = 0; fn < 4; ++fn)
#pragma unroll
            for (int r = 0; r < 4; ++r) {
                float g = accg[fm][fn][r];
                float u = accu[fm][fn][r];
                float h = (g / (1.f + __expf(-g))) * u;
                const int row_l = wr * 64 + fm * 16 + ehr * 4 + r;
                const int col_l = wc * 64 + fn * 16 + col16;
                bounce[row_l * 136 + col_l] = (bf16_t)h;
            }
    ASM_LGKM0;
    ASM_BAR;
    const size_t hblk = (size_t)mt * (Nb / 32) + (n0 >> 5);
#pragma unroll
    for (int j = 0; j < 8; ++j) {
        const int u = j * 512 + tid;
        const int ktl = u >> 10, rg = (u >> 6) & 15, ln = u & 63;
        u32x4 v = *(const u32x4*)((const char*)bounce +
                                  (size_t)(rg * 16 + (ln & 15)) * 272 + ktl * 64 + (ln >> 4) * 16);
        *(u32x4*)(hp + ((hblk + ktl) << 13) + (rg << 9) + (ln << 3)) = v;
    }
}

// ============================================================================
// down GEMM. A = h packed bf16 (gload), B = Wd packed bf16 (gload).
// BM=256 BN=128 BK=32, 8 waves, 4-buf ring, 1 barrier/tile. Out f32 row-major.
// ============================================================================
template <int KDIM>
__global__ __launch_bounds__(512, 2) void k_down(const bf16_t* __restrict__ hp,
                                                 const bf16_t* __restrict__ Wd,
                                                 float* __restrict__ out, int Nb) {
    constexpr int NT = KDIM / 32;
    __shared__ char smem[98304];  // A: 4x16KB @0; B: 4x8KB @64K

    const int tid = threadIdx.x, lane = tid & 63, wid = tid >> 6;
    const int wr = wid >> 1, wc = wid & 1;
    int mt, ntile;
    decode_tile(Nb >> 7, mt, ntile);
    const int m0 = mt * 256, n0 = ntile * 128;

    f32x4 acc[4][4];
#pragma unroll
    for (int i = 0; i < 4; ++i)
#pragma unroll
        for (int j = 0; j < 4; ++j) acc[i][j] = (f32x4)0.f;

    const bf16_t* hpB = hp + (((size_t)mt * NT) << 13);
    const bf16_t* wdB = Wd + (((size_t)ntile * NT) << 12);
    const u32 lseg = (u32)(lane << 3);

    auto issue = [&](int kt) {
        char* ab = smem + ((kt & 3) << 14);
        char* bb = smem + 65536 + ((kt & 3) << 13);
        const bf16_t* as = hpB + (((size_t)kt) << 13);
        const bf16_t* bs = wdB + (((size_t)kt) << 12);
        gload16(as + ((wid * 2 + 0) << 9) + lseg, ab + ((wid * 2 + 0) << 10));
        gload16(as + ((wid * 2 + 1) << 9) + lseg, ab + ((wid * 2 + 1) << 10));
        gload16(bs + (wid << 9) + lseg, bb + (wid << 10));
    };

    issue(0); issue(1); issue(2);
    ASM_VMCNT6;  // batch0 landed
    ASM_BAR;

    for (int t = 0; t < NT; ++t) {
        const char* abuf = smem + ((t & 3) << 14);
        const char* bbuf = smem + 65536 + ((t & 3) << 13);
        const u32 fo = (u32)(lane << 4);
        bf16x8 fa[4], fb[4];
#pragma unroll
        for (int f = 0; f < 4; ++f) {
            fa[f] = *(const bf16x8*)(abuf + (((wr * 4 + f) << 10) + fo));
            fb[f] = *(const bf16x8*)(bbuf + (((wc * 4 + f) << 10) + fo));
        }
        if (t <= NT - 3) { ASM_VMCNT3; } else { ASM_VMCNT0; }
        if (t + 3 < NT) issue(t + 3);
        // no full lgkm drain: fine-grained compiler waits per MFMA operand
        __builtin_amdgcn_s_setprio(1);
#pragma unroll
        for (int fn = 0; fn < 4; ++fn)
#pragma unroll
            for (int fm = 0; fm < 4; ++fm)
                acc[fm][fn] = __builtin_amdgcn_mfma_f32_16x16x32_bf16(fa[fm], fb[fn], acc[fm][fn], 0, 0, 0);
        __builtin_amdgcn_s_setprio(0);
        ASM_LGKM0;
        ASM_BAR;
    }

    const int ehr = lane >> 4, col16 = lane & 15;
#pragma unroll
    for (int fm = 0; fm < 4; ++fm)
#pragma unroll
        for (int fn = 0; fn < 4; ++fn) {
            const int col = n0 + wc * 64 + fn * 16 + col16;
#pragma unroll
            for (int r = 0; r < 4; ++r) {
                const int row = m0 + wr * 64 + fm * 16 + ehr * 4 + r;
                out[(size_t)row * Nb + col] = acc[fm][fn][r];
            }
        }
}

// ============================================================================
extern "C" void kernel_launch(void* const* d_in, const int* in_sizes, int n_in,
                              void* d_out, int out_size, void* d_ws, size_t ws_size,
                              hipStream_t stream) {
    const float* x      = (const float*)d_in[0];
    const int*   gate_q = (const int*)d_in[1];
    const float* gate_s = (const float*)d_in[2];
    const int*   up_q   = (const int*)d_in[3];
    const float* up_s   = (const float*)d_in[4];
    const int*   down_q = (const int*)d_in[5];
    const float* down_s = (const float*)d_in[6];
    float*       out    = (float*)d_out;

    const int  H = H_DIM, I = I_DIM;
    const long M = (long)in_sizes[0] / H;  // 8192

    char*        ws = (char*)d_ws;
    const size_t wb = (size_t)H * I * sizeof(bf16_t);  // 90.2 MB per weight
    bf16_t* wg = (bf16_t*)ws;
    bf16_t* wu = (bf16_t*)(ws + wb);
    bf16_t* wd = (bf16_t*)(ws + 2 * wb);
    bf16_t* hp = (bf16_t*)(ws + 3 * wb);

    // token chunk sized to remaining workspace (ws >= 517MB proven in round 2)
    long avail = (long)ws_size - (long)(3 * wb);
    long C = avail > 0 ? avail / ((long)I * (long)sizeof(bf16_t)) : 256;
    C = (C / 256) * 256;
    if (C > M) C = M;
    if (C < 256) C = 256;

    dim3 dq1(H / 32, I / 128);
    k_dequant_pack<<<dq1, 256, 0, stream>>>(gate_q, gate_s, wg, H, I);
    k_dequant_pack<<<dq1, 256, 0, stream>>>(up_q, up_s, wu, H, I);
    dim3 dq2(I / 32, H / 128);
    k_dequant_pack<<<dq2, 256, 0, stream>>>(down_q, down_s, wd, I, H);

    for (long c0 = 0; c0 < M; c0 += C) {
        const long mc = (M - c0 < C) ? (M - c0) : C;
        const unsigned g1 = (unsigned)((mc / 256) * (I / 128));
        k_gateup<H_DIM><<<g1, 512, 0, stream>>>(x + (size_t)c0 * H, wg, wu, hp, I);
        const unsigned g2 = (unsigned)((mc / 256) * (H / 128));
        k_down<I_DIM><<<g2, 512, 0, stream>>>(hp, wd, out + (size_t)c0 * H, H);
    }
}

// Round 9
// 2410.348 us; speedup vs baseline: 1.1417x; 1.1417x over previous
//
#include <hip/hip_runtime.h>
#include <hip/hip_bf16.h>
#include <cstdint>
#include <cstddef>

typedef __bf16 bf16_t;
typedef __bf16 bf16x8 __attribute__((ext_vector_type(8)));
typedef float f32x4 __attribute__((ext_vector_type(4)));
typedef unsigned int u32;
typedef u32 u32x4 __attribute__((ext_vector_type(4)));

#define H_DIM 4096
#define I_DIM 11008

__device__ __forceinline__ u32 pack_bf16(float a, float b) {
    union { __bf16 h[2]; u32 u; } r;
    r.h[0] = (__bf16)a;
    r.h[1] = (__bf16)b;
    return r.u;
}

// async global->LDS: each lane 16B; LDS dest = wave-uniform base + lane*16
__device__ __forceinline__ void gload16(const bf16_t* g, char* l) {
    __builtin_amdgcn_global_load_lds(
        (const __attribute__((address_space(1))) u32*)g,
        (__attribute__((address_space(3))) u32*)l, 16, 0, 0);
}

#define ASM_VMCNT4 asm volatile("s_waitcnt vmcnt(4)" ::: "memory")
#define ASM_VMCNT3 asm volatile("s_waitcnt vmcnt(3)" ::: "memory")
#define ASM_VMCNT0 asm volatile("s_waitcnt vmcnt(0)" ::: "memory")
#define ASM_LGKM0  asm volatile("s_waitcnt lgkmcnt(0)" ::: "memory")
#define ASM_BAR    asm volatile("s_barrier" ::: "memory")
#define SCHED_FENCE __builtin_amdgcn_sched_barrier(0)

// ============================================================================
// dequant + pack: Q[K][N] int codes, S[K/128][N] -> W packed fragment order.
// Block = one B-block (32 k x 128 n). Packed unit (cg,lane) holds
// element (n = cg*16 + (lane&15), k = (lane>>4)*8 + e), block stride 4096 elems.
// ============================================================================
__global__ __launch_bounds__(256) void k_dequant_pack(const int* __restrict__ Q,
                                                      const float* __restrict__ S,
                                                      bf16_t* __restrict__ W,
                                                      int K, int N) {
    __shared__ bf16_t tile[128][40];
    const int tid = threadIdx.x;
    const int k0 = blockIdx.x * 32, n0 = blockIdx.y * 128;
    const int grp = k0 >> 7;
    const int c4 = (tid & 31) * 4;
    const int kr = tid >> 5;
    float4 sc = *(const float4*)(S + (size_t)grp * N + n0 + c4);
#pragma unroll
    for (int p = 0; p < 4; ++p) {
        const int k = kr + p * 8;
        int4 q = *(const int4*)(Q + (size_t)(k0 + k) * N + n0 + c4);
        tile[c4 + 0][k] = (bf16_t)fmaf((float)q.x, sc.x, -8.f * sc.x);
        tile[c4 + 1][k] = (bf16_t)fmaf((float)q.y, sc.y, -8.f * sc.y);
        tile[c4 + 2][k] = (bf16_t)fmaf((float)q.z, sc.z, -8.f * sc.z);
        tile[c4 + 3][k] = (bf16_t)fmaf((float)q.w, sc.w, -8.f * sc.w);
    }
    __syncthreads();
    bf16_t* blk = W + (((size_t)blockIdx.y * (K / 32) + blockIdx.x) << 12);
#pragma unroll
    for (int j = 0; j < 2; ++j) {
        const int u = j * 256 + tid;
        const int cg = u >> 6, ln = u & 63;
        u32x4 v = *(const u32x4*)((const char*)tile +
                                  (size_t)(cg * 16 + (ln & 15)) * 80 + (ln >> 4) * 16);
        *(u32x4*)(blk + (cg << 9) + (ln << 3)) = v;
    }
}

// ============================================================================
// x f32 -> bf16 packed A-fragment layout.
// Block = one A-block (256 rows x 32 k). Packed unit (u,lane) holds
// element (row = u*16 + (lane&15), k = (lane>>4)*8 + e), block stride 8192.
// ============================================================================
__global__ __launch_bounds__(256) void k_cvt_pack(const float* __restrict__ x,
                                                  bf16_t* __restrict__ xp, int K) {
    __shared__ bf16_t tile[256][40];
    const int tid = threadIdx.x;
    const int m0 = blockIdx.x * 256, k0 = blockIdx.y * 32;
    const int rr = tid >> 3, kq = (tid & 7) * 4;
#pragma unroll
    for (int p = 0; p < 8; ++p) {
        const int row = rr + p * 32;
        float4 v = *(const float4*)(x + (size_t)(m0 + row) * K + k0 + kq);
        uint2 o;
        o.x = pack_bf16(v.x, v.y);
        o.y = pack_bf16(v.z, v.w);
        *(uint2*)&tile[row][kq] = o;
    }
    __syncthreads();
    bf16_t* blk = xp + (((size_t)blockIdx.x * (K / 32) + blockIdx.y) << 13);
#pragma unroll
    for (int j = 0; j < 4; ++j) {
        const int u = j * 256 + tid;
        const int un = u >> 6, ln = u & 63;
        u32x4 v = *(const u32x4*)((const char*)tile +
                                  (size_t)(un * 16 + (ln & 15)) * 80 + (ln >> 4) * 16);
        *(u32x4*)(blk + (un << 9) + (ln << 3)) = v;
    }
}

// ============================================================================
// fused gate+up GEMM. A = xp packed bf16, B0/B1 packed bf16 (all gload_lds).
// BM=256 BN=128 BK=32, 8 waves (4x2), 4-buf ring, 1 barrier/tile,
// register-fragment double buffer: read frags(t+1) BEFORE MFMA(t).
// vmcnt tail rule: the end-of-body wait must retire tile t+2 (read next
// body). When issue(t+3) is skipped (tail), only tile t+2's ops are
// outstanding, so a counted wait is a no-op -> must drain to 0.
// ============================================================================
template <int KDIM>
__global__ __launch_bounds__(512, 2) void k_gateup(const bf16_t* __restrict__ xp,
                                                   const bf16_t* __restrict__ Wg,
                                                   const bf16_t* __restrict__ Wu,
                                                   bf16_t* __restrict__ hp, int Nb) {
    constexpr int NT = KDIM / 32;
    __shared__ char smem[131072];  // A: 4x16KB @0; B0: 4x8KB @64K; B1: 4x8KB @96K

    const int tid = threadIdx.x, lane = tid & 63, wid = tid >> 6;
    const int wr = wid >> 1, wc = wid & 1;
    const int mt = blockIdx.x, ntile = blockIdx.y;
    const int n0 = ntile * 128;

    f32x4 accg[4][4], accu[4][4];
#pragma unroll
    for (int i = 0; i < 4; ++i)
#pragma unroll
        for (int j = 0; j < 4; ++j) { accg[i][j] = (f32x4)0.f; accu[i][j] = (f32x4)0.f; }

    const bf16_t* xA  = xp + (((size_t)mt * NT) << 13);
    const bf16_t* wgB = Wg + (((size_t)ntile * NT) << 12);
    const bf16_t* wuB = Wu + (((size_t)ntile * NT) << 12);
    const u32 bseg = (u32)((wid << 9) + (lane << 3));
    const u32 lseg = (u32)(lane << 3);

    auto issue = [&](int kt) {
        char* ab = smem + ((kt & 3) << 14);
        char* b0 = smem + 65536 + ((kt & 3) << 13);
        char* b1 = smem + 98304 + ((kt & 3) << 13);
        const bf16_t* as = xA + (((size_t)kt) << 13);
        gload16(as + ((wid * 2 + 0) << 9) + lseg, ab + ((wid * 2 + 0) << 10));
        gload16(as + ((wid * 2 + 1) << 9) + lseg, ab + ((wid * 2 + 1) << 10));
        gload16(wgB + (((size_t)kt) << 12) + bseg, b0 + (wid << 10));
        gload16(wuB + (((size_t)kt) << 12) + bseg, b1 + (wid << 10));
    };
    // frag set: [0..3]=A, [4..7]=B0, [8..11]=B1
    auto readf = [&](int kt, bf16x8 (&fr)[12]) {
        const char* ab = smem + ((kt & 3) << 14);
        const char* b0 = smem + 65536 + ((kt & 3) << 13);
        const char* b1 = smem + 98304 + ((kt & 3) << 13);
        const u32 fo = (u32)(lane << 4);
#pragma unroll
        for (int f = 0; f < 4; ++f) {
            fr[f]     = *(const bf16x8*)(ab + (((wr * 4 + f) << 10) + fo));
            fr[4 + f] = *(const bf16x8*)(b0 + (((wc * 4 + f) << 10) + fo));
            fr[8 + f] = *(const bf16x8*)(b1 + (((wc * 4 + f) << 10) + fo));
        }
    };
    auto body = [&](int t, bf16x8 (&cur)[12], bf16x8 (&nxt)[12]) {
        if (t + 1 < NT) readf(t + 1, nxt);
        SCHED_FENCE;  // keep next-tile ds_reads issued before the MFMA cluster
        __builtin_amdgcn_s_setprio(1);
#pragma unroll
        for (int fn = 0; fn < 4; ++fn)
#pragma unroll
            for (int fm = 0; fm < 4; ++fm) {
                accg[fm][fn] = __builtin_amdgcn_mfma_f32_16x16x32_bf16(cur[fm], cur[4 + fn], accg[fm][fn], 0, 0, 0);
                accu[fm][fn] = __builtin_amdgcn_mfma_f32_16x16x32_bf16(cur[fm], cur[8 + fn], accu[fm][fn], 0, 0, 0);
            }
        __builtin_amdgcn_s_setprio(0);
        if (t + 3 < NT) {
            issue(t + 3);
            ASM_VMCNT4;   // {t+2,t+3} outstanding -> retire tile t+2
        } else {
            ASM_VMCNT0;   // tail: counted wait would be a no-op -> full drain
        }
        ASM_BAR;
    };

    bf16x8 fA[12], fB[12];
    issue(0); issue(1); issue(2);
    ASM_VMCNT4;  // tiles 0 AND 1 landed (12 outstanding -> retire oldest 8)
    ASM_BAR;
    readf(0, fA);

    for (int t = 0; t < NT; t += 2) {
        body(t, fA, fB);
        body(t + 1, fB, fA);
    }

    // ---- epilogue: silu(g)*u -> bf16, bounce via LDS, write packed h ----
    bf16_t* bounce = (bf16_t*)smem;  // [256][136] bf16 = 69632B
    const int ehr = lane >> 4, col16 = lane & 15;
#pragma unroll
    for (int fm = 0; fm < 4; ++fm)
#pragma unroll
        for (int fn = 0; fn < 4; ++fn)
#pragma unroll
            for (int r = 0; r < 4; ++r) {
                float g = accg[fm][fn][r];
                float u = accu[fm][fn][r];
                float h = (g / (1.f + __expf(-g))) * u;
                const int row_l = wr * 64 + fm * 16 + ehr * 4 + r;
                const int col_l = wc * 64 + fn * 16 + col16;
                bounce[row_l * 136 + col_l] = (bf16_t)h;
            }
    ASM_LGKM0;
    ASM_BAR;
    const size_t hblk = (size_t)mt * (Nb / 32) + (n0 >> 5);
#pragma unroll
    for (int j = 0; j < 8; ++j) {
        const int u = j * 512 + tid;
        const int ktl = u >> 10, rg = (u >> 6) & 15, ln = u & 63;
        u32x4 v = *(const u32x4*)((const char*)bounce +
                                  (size_t)(rg * 16 + (ln & 15)) * 272 + ktl * 64 + (ln >> 4) * 16);
        *(u32x4*)(hp + ((hblk + ktl) << 13) + (rg << 9) + (ln << 3)) = v;
    }
}

// ============================================================================
// down GEMM. A = h packed bf16, B = Wd packed bf16 (all gload_lds).
// Same skeleton: 4-buf ring, reg-frag double buffer, 1 barrier/tile.
// ============================================================================
template <int KDIM>
__global__ __launch_bounds__(512, 2) void k_down(const bf16_t* __restrict__ hp,
                                                 const bf16_t* __restrict__ Wd,
                                                 float* __restrict__ out, int Nb) {
    constexpr int NT = KDIM / 32;
    __shared__ char smem[98304];  // A: 4x16KB @0; B: 4x8KB @64K

    const int tid = threadIdx.x, lane = tid & 63, wid = tid >> 6;
    const int wr = wid >> 1, wc = wid & 1;
    const int mt = blockIdx.x, ntile = blockIdx.y;
    const int m0 = mt * 256, n0 = ntile * 128;

    f32x4 acc[4][4];
#pragma unroll
    for (int i = 0; i < 4; ++i)
#pragma unroll
        for (int j = 0; j < 4; ++j) acc[i][j] = (f32x4)0.f;

    const bf16_t* hpB = hp + (((size_t)mt * NT) << 13);
    const bf16_t* wdB = Wd + (((size_t)ntile * NT) << 12);
    const u32 lseg = (u32)(lane << 3);

    auto issue = [&](int kt) {
        char* ab = smem + ((kt & 3) << 14);
        char* bb = smem + 65536 + ((kt & 3) << 13);
        const bf16_t* as = hpB + (((size_t)kt) << 13);
        const bf16_t* bs = wdB + (((size_t)kt) << 12);
        gload16(as + ((wid * 2 + 0) << 9) + lseg, ab + ((wid * 2 + 0) << 10));
        gload16(as + ((wid * 2 + 1) << 9) + lseg, ab + ((wid * 2 + 1) << 10));
        gload16(bs + (wid << 9) + lseg, bb + (wid << 10));
    };
    // frag set: [0..3]=A, [4..7]=B
    auto readf = [&](int kt, bf16x8 (&fr)[8]) {
        const char* ab = smem + ((kt & 3) << 14);
        const char* bb = smem + 65536 + ((kt & 3) << 13);
        const u32 fo = (u32)(lane << 4);
#pragma unroll
        for (int f = 0; f < 4; ++f) {
            fr[f]     = *(const bf16x8*)(ab + (((wr * 4 + f) << 10) + fo));
            fr[4 + f] = *(const bf16x8*)(bb + (((wc * 4 + f) << 10) + fo));
        }
    };
    auto body = [&](int t, bf16x8 (&cur)[8], bf16x8 (&nxt)[8]) {
        if (t + 1 < NT) readf(t + 1, nxt);
        SCHED_FENCE;
        __builtin_amdgcn_s_setprio(1);
#pragma unroll
        for (int fn = 0; fn < 4; ++fn)
#pragma unroll
            for (int fm = 0; fm < 4; ++fm)
                acc[fm][fn] = __builtin_amdgcn_mfma_f32_16x16x32_bf16(cur[fm], cur[4 + fn], acc[fm][fn], 0, 0, 0);
        __builtin_amdgcn_s_setprio(0);
        if (t + 3 < NT) {
            issue(t + 3);
            ASM_VMCNT3;   // {t+2,t+3} outstanding -> retire tile t+2
        } else {
            ASM_VMCNT0;   // tail: full drain (counted wait would be a no-op)
        }
        ASM_BAR;
    };

    bf16x8 fA[8], fB[8];
    issue(0); issue(1); issue(2);
    ASM_VMCNT3;  // tiles 0,1 landed (9 outstanding -> retire oldest 6)
    ASM_BAR;
    readf(0, fA);

    for (int t = 0; t < NT; t += 2) {
        body(t, fA, fB);
        body(t + 1, fB, fA);
    }

    const int ehr = lane >> 4, col16 = lane & 15;
#pragma unroll
    for (int fm = 0; fm < 4; ++fm)
#pragma unroll
        for (int fn = 0; fn < 4; ++fn) {
            const int col = n0 + wc * 64 + fn * 16 + col16;
#pragma unroll
            for (int r = 0; r < 4; ++r) {
                const int row = m0 + wr * 64 + fm * 16 + ehr * 4 + r;
                out[(size_t)row * Nb + col] = acc[fm][fn][r];
            }
        }
}

// ============================================================================
extern "C" void kernel_launch(void* const* d_in, const int* in_sizes, int n_in,
                              void* d_out, int out_size, void* d_ws, size_t ws_size,
                              hipStream_t stream) {
    const float* x      = (const float*)d_in[0];
    const int*   gate_q = (const int*)d_in[1];
    const float* gate_s = (const float*)d_in[2];
    const int*   up_q   = (const int*)d_in[3];
    const float* up_s   = (const float*)d_in[4];
    const int*   down_q = (const int*)d_in[5];
    const float* down_s = (const float*)d_in[6];
    float*       out    = (float*)d_out;

    const int  H = H_DIM, I = I_DIM;
    const long M = (long)in_sizes[0] / H;  // 8192

    char*        ws = (char*)d_ws;
    const size_t wb  = (size_t)H * I * sizeof(bf16_t);  // 90.2 MB per weight
    const size_t xpb = (size_t)M * H * sizeof(bf16_t);  // 67 MB
    bf16_t* wg = (bf16_t*)ws;
    bf16_t* wu = (bf16_t*)(ws + wb);
    bf16_t* wd = (bf16_t*)(ws + 2 * wb);
    bf16_t* xpk = (bf16_t*)(ws + 3 * wb);
    bf16_t* hp  = (bf16_t*)(ws + 3 * wb + xpb);

    long avail = (long)ws_size - (long)(3 * wb + xpb);
    long C = avail > 0 ? avail / ((long)I * (long)sizeof(bf16_t)) : 256;
    C = (C / 256) * 256;
    if (C > M) C = M;
    if (C < 256) C = 256;

    dim3 dq1(H / 32, I / 128);
    k_dequant_pack<<<dq1, 256, 0, stream>>>(gate_q, gate_s, wg, H, I);
    k_dequant_pack<<<dq1, 256, 0, stream>>>(up_q, up_s, wu, H, I);
    dim3 dq2(I / 32, H / 128);
    k_dequant_pack<<<dq2, 256, 0, stream>>>(down_q, down_s, wd, I, H);
    dim3 dcv((unsigned)(M / 256), H / 32);
    k_cvt_pack<<<dcv, 256, 0, stream>>>(x, xpk, H);

    for (long c0 = 0; c0 < M; c0 += C) {
        const long mc = (M - c0 < C) ? (M - c0) : C;
        dim3 g1((unsigned)(mc / 256), (unsigned)(I / 128));
        k_gateup<H_DIM><<<g1, 512, 0, stream>>>(xpk + (size_t)(c0 / 256) * ((size_t)H_DIM / 32 << 13),
                                                wg, wu, hp, I);
        dim3 g2((unsigned)(mc / 256), (unsigned)(H / 128));
        k_down<I_DIM><<<g2, 512, 0, stream>>>(hp, wd, out + (size_t)c0 * H, H);
    }
}